// Round 1
// baseline (364.268 us; speedup 1.0000x reference)
//
#include <hip/hip_runtime.h>
#include <hip/hip_bf16.h>
#include <float.h>

// z: (64, 256, 32, 32) fp32 ; emb: (1024, 256) fp32
// M = 65536 pixels, D = 256, K = 1024 codes
// out: [z_q (16777216 f)] [indices as float (65536)] [vq_loss (1)]
#define OUT_IDX_OFF 16777216
#define OUT_LOSS_OFF 16842752
// scratch inside d_out's z_q region (overwritten by k_out at the end):
// A2 bf16: floats [0, 8388608)
// cand pairs (s,k) float2: floats [8388608, 12582912)  65536 rows x 32 slots
// gmin (int-punned f32):   floats [12582912, 13107200)
// gcnt (int):              floats [13107200, 13631488)
#define CAND_OFF 8388608
#define GMIN_OFF 12582912
#define GCNT_OFF 13107200
#define NSLOT 32
#define DELTA 2.0e-3f

typedef __attribute__((ext_vector_type(8))) short short8;
typedef __attribute__((ext_vector_type(4))) float f32x4;

static __device__ __forceinline__ unsigned short f2bf(float f) {
  union { __hip_bfloat16 h; unsigned short u; } cv;
  cv.h = __float2bfloat16(f);
  return cv.u;
}

// ---------------------------------------------------------------------------
// P1: emb -> E2 bf16 [1024 codes][256 d] + exact cws (proven r1-r4).
// ---------------------------------------------------------------------------
__global__ __launch_bounds__(256) void k_prep(const float* __restrict__ emb,
                                              unsigned short* __restrict__ E2,
                                              float* __restrict__ cws) {
  const int k = blockIdx.x, d = threadIdx.x;
  const float v = emb[k * 256 + d];
  __shared__ float red[256];
  __shared__ unsigned short row[256];
  row[d] = f2bf(v);
  red[d] = v * v;
  __syncthreads();
  for (int s = 128; s > 0; s >>= 1) {
    if (d < s) red[d] += red[d + s];
    __syncthreads();
  }
  if (d == 0) cws[k] = red[0];
  if (d < 32) ((short8*)&E2[k * 256])[d] = ((short8*)row)[d];
}

// ---------------------------------------------------------------------------
// P2 v2: z (NCHW) -> A2 bf16 [pixel][256]. 64px x 64d tiles; float4 loads
// fully coalesced along hw; LDS transpose (2-way bank aliasing only = free);
// short8 stores. (unchanged, proven)
// ---------------------------------------------------------------------------
__global__ __launch_bounds__(256) void k_cvt2(const float* __restrict__ z,
                                              unsigned short* __restrict__ A2) {
  __shared__ float tile[64][65];
  const int t = threadIdx.x;
  const int pt = blockIdx.x >> 2, dt = blockIdx.x & 3;
  const int p0 = pt << 6, d0 = dt << 6;
  const int n = p0 >> 10, hw0 = p0 & 1023;
  const float* zb = z + (size_t)n * 262144 + (size_t)d0 * 1024 + hw0;
  const int hwl = (t & 15) << 2;
#pragma unroll
  for (int i = 0; i < 4; ++i) {
    const int dl = (t >> 4) + i * 16;
    const float4 v = *(const float4*)&zb[(size_t)dl * 1024 + hwl];
    tile[hwl + 0][dl] = v.x;
    tile[hwl + 1][dl] = v.y;
    tile[hwl + 2][dl] = v.z;
    tile[hwl + 3][dl] = v.w;
  }
  __syncthreads();
  const int pl = t >> 2, c = t & 3;
  unsigned short* dst = &A2[(size_t)(p0 + pl) * 256 + d0];
#pragma unroll
  for (int h = 0; h < 2; ++h) {
    const int ch = c + h * 4;
    unsigned short tmp[8];
#pragma unroll
    for (int j = 0; j < 8; ++j) tmp[j] = f2bf(tile[pl][ch * 8 + j]);
    *(short8*)&dst[ch * 8] = *(short8*)tmp;
  }
}

// ---------------------------------------------------------------------------
// k_a: exact numpy-pairwise ||x||^2 (proven, unchanged).
// ---------------------------------------------------------------------------
__global__ __launch_bounds__(256) void k_a(const float* __restrict__ z,
                                           float* __restrict__ aws) {
#pragma clang fp contract(off)
  const int t = threadIdx.x;
  const int r = (blockIdx.x << 7) + (t & 127);
  const int h = t >> 7;
  const int n = r >> 10;
  const int hw = r & 1023;
  const float* zp = z + (size_t)n * 262144 + hw + (size_t)h * 131072;
  float acc[8];
#pragma unroll
  for (int j = 0; j < 8; ++j) {
    const float x = zp[(size_t)j * 1024];
    acc[j] = x * x;
  }
  for (int g = 1; g < 16; ++g) {
#pragma unroll
    for (int j = 0; j < 8; ++j) {
      const float x = zp[(size_t)(g * 8 + j) * 1024];
      const float p = x * x;
      acc[j] = acc[j] + p;
    }
  }
  const float s = ((acc[0] + acc[1]) + (acc[2] + acc[3])) +
                  ((acc[4] + acc[5]) + (acc[6] + acc[7]));
  __shared__ float red[256];
  red[t] = s;
  __syncthreads();
  if (t < 128) aws[(blockIdx.x << 7) + t] = red[t] + red[t + 128];
}

// ---------------------------------------------------------------------------
// k_gemm3: block-owns-row restructure of the MFMA prefilter.
//   - 1024 blocks x 256 thr; each block owns 64 rows, sweeps all 8 col-chunks.
//   - A tile (64x256 bf16) staged ONCE via global_load_lds (pre-swizzled
//     per-lane SOURCE, linear LDS dest -- m173 pattern), then lifted into
//     registers (16 short8 = 64 VGPR/lane). A LDS region recycled as the B
//     double-buffer => LDS 37.3KB, 3 blocks/CU.
//   - B streamed as 32 slices of 16KB via global_load_lds, 2-phase pipeline
//     (issue next -> compute current -> __syncthreads).
//   - Score chain s = a + fmaf(-2, acc, c) and MFMA accumulation order (kt
//     0..3, ks 0..1) are BIT-IDENTICAL to k_gemm2 => identical gmin bits and
//     candidate values; k_finish unchanged.
//   - All min/count state in LDS; single writer per row => no global atomics,
//     no gmin/gcnt memsets.
// ---------------------------------------------------------------------------
__global__ __launch_bounds__(256, 3) void k_gemm3(
    const unsigned short* __restrict__ A2, const unsigned short* __restrict__ E2,
    const float* __restrict__ cws, const float* __restrict__ aws,
    int* __restrict__ gmin, int* __restrict__ gcnt,
    float2* __restrict__ gcand) {
  // Bs double buffer (2 x 16KB); the full 32KB array also serves as the
  // one-shot A staging area during the prologue.
  __shared__ __align__(16) unsigned short Bs[2][8192];
  __shared__ float c_all[1024];
  __shared__ float a_l[64];
  __shared__ float rmin_s[64];
  __shared__ int rcnt_s[64];
  __shared__ float rmkt[128];  // [row][wc]

  const int t = threadIdx.x;
  const int lane = t & 63;
  const int wv = __builtin_amdgcn_readfirstlane(t >> 6);
  const int wr = wv >> 1, wc = wv & 1;
  const int quad = lane >> 4, l15 = lane & 15;
  const int sw7 = l15 & 7;
  const int r0 = blockIdx.x << 6;

  unsigned short* As = &Bs[0][0];  // 64 rows x 256 d bf16 = 32KB (aliases Bs)

  // ---- prologue: A tile -> LDS (swizzled) via global_load_lds.
  // LDS dest is linear (wave-uniform base + lane*16B); the swizzle lives in
  // the per-lane SOURCE address: physical granule gpos of row holds source
  // granule (gpos&24)|((gpos&7)^(row&7))  (involution).
#pragma unroll
  for (int i = 0; i < 8; ++i) {
    const int blk = (wv << 3) + i;
    const int L = (blk << 6) + lane;
    const int row = L >> 5, gpos = L & 31;
    const int gsrc = (gpos & 24) | ((gpos & 7) ^ (row & 7));
    const unsigned short* src = A2 + (((size_t)(r0 + row)) << 8) + (gsrc << 3);
    __builtin_amdgcn_global_load_lds(
        (const __attribute__((address_space(1))) void*)src,
        (__attribute__((address_space(3))) void*)(As + (blk << 9)), 16, 0, 0);
  }
  ((f32x4*)c_all)[t] = ((const f32x4*)cws)[t];
  if (t < 64) {
    a_l[t] = aws[r0 + t];
    rmin_s[t] = FLT_MAX;
    rcnt_s[t] = 0;
  }
  __syncthreads();  // A landed (vmcnt drained), inits visible

  // ---- lift A fragments into registers (read once; LDS recycled for B)
  short8 af[16];
#pragma unroll
  for (int tr = 0; tr < 2; ++tr)
#pragma unroll
    for (int kst = 0; kst < 8; ++kst) {
      const int rr = (wr << 5) + (tr << 4) + l15;
      const int g = (kst << 2) + quad;
      const int gphys = (g & 24) | ((g & 7) ^ (rr & 7));
      af[tr * 8 + kst] = *(const short8*)&As[rr * 256 + (gphys << 3)];
    }
  __syncthreads();  // all waves done reading A; B staging may overwrite

  // per-thread B staging constants (dest linear, source pre-swizzled)
  int bdst[4], bsrc[4];
#pragma unroll
  for (int i = 0; i < 4; ++i) {
    const int blk = (wv << 2) + i;
    const int L = (blk << 6) + lane;
    const int col = L >> 3, gpos = L & 7;
    bdst[i] = blk << 9;                                 // shorts
    bsrc[i] = (col << 8) + ((gpos ^ (col & 7)) << 3);   // shorts within E2
  }

  auto stageB = [&](unsigned short* dst, int k0s, int kts) {
#pragma unroll
    for (int i = 0; i < 4; ++i) {
      const unsigned short* src = E2 + (k0s << 8) + bsrc[i] + (kts << 6);
      __builtin_amdgcn_global_load_lds(
          (const __attribute__((address_space(1))) void*)src,
          (__attribute__((address_space(3))) void*)(dst + bdst[i]), 16, 0, 0);
    }
  };

  f32x4 acc[2][4];
#pragma unroll
  for (int a = 0; a < 2; ++a)
#pragma unroll
    for (int b = 0; b < 4; ++b) acc[a][b] = (f32x4)(0.0f);

  stageB(&Bs[0][0], 0, 0);
  __syncthreads();  // slice 0 ready

  for (int ck = 0; ck < 8; ++ck) {
    const int k0 = ck << 7;
#pragma unroll
    for (int kt = 0; kt < 4; ++kt) {
      // issue next slice into the other buffer (overlaps with compute)
      if (kt < 3)
        stageB(&Bs[(kt + 1) & 1][0], k0, kt + 1);
      else if (ck < 7)
        stageB(&Bs[0][0], k0 + 128, 0);

      // compute current slice (buf parity = kt&1, compile-time)
      const unsigned short* bs = &Bs[kt & 1][0];
#pragma unroll
      for (int ks = 0; ks < 2; ++ks) {
        short8 bfr[4];
#pragma unroll
        for (int tc = 0; tc < 4; ++tc) {
          const int col = (wc << 6) + (tc << 4) + l15;
          const int gphys = ((ks << 2) + quad) ^ sw7;
          bfr[tc] = *(const short8*)&bs[col * 64 + (gphys << 3)];
        }
#pragma unroll
        for (int tr = 0; tr < 2; ++tr)
#pragma unroll
          for (int tc = 0; tc < 4; ++tc)
            acc[tr][tc] = __builtin_amdgcn_mfma_f32_16x16x32_bf16(
                af[tr * 8 + kt * 2 + ks], bfr[tc], acc[tr][tc], 0, 0, 0);
      }

      if (kt == 3) {
        // ---- chunk epilogue: pass 1 (chunk-local per-row min)
#pragma unroll
        for (int tr = 0; tr < 2; ++tr)
#pragma unroll
          for (int rg = 0; rg < 4; ++rg) {
            const int rloc = (wr << 5) + (tr << 4) + (quad << 2) + rg;
            const float av = a_l[rloc];
            float mn = FLT_MAX;
#pragma unroll
            for (int tc = 0; tc < 4; ++tc) {
              const int k = k0 + (wc << 6) + (tc << 4) + l15;
              const float s = av + fmaf(-2.0f, acc[tr][tc][rg], c_all[k]);
              mn = fminf(mn, s);
            }
            mn = fminf(mn, __shfl_xor(mn, 1));
            mn = fminf(mn, __shfl_xor(mn, 2));
            mn = fminf(mn, __shfl_xor(mn, 4));
            mn = fminf(mn, __shfl_xor(mn, 8));
            if (l15 == 0) rmkt[rloc * 2 + wc] = mn;
          }
        __syncthreads();
        if (t < 64)
          rmin_s[t] = fminf(rmin_s[t], fminf(rmkt[t * 2], rmkt[t * 2 + 1]));
        __syncthreads();
        // pass 2: append candidates within DELTA of running min (winner
        // provably appended: s_w <= rmin_final + DELTA <= rmin_now + DELTA)
#pragma unroll
        for (int tr = 0; tr < 2; ++tr)
#pragma unroll
          for (int rg = 0; rg < 4; ++rg) {
            const int rloc = (wr << 5) + (tr << 4) + (quad << 2) + rg;
            const float av = a_l[rloc];
            const float lim = rmin_s[rloc] + DELTA;
#pragma unroll
            for (int tc = 0; tc < 4; ++tc) {
              const int k = k0 + (wc << 6) + (tc << 4) + l15;
              const float s = av + fmaf(-2.0f, acc[tr][tc][rg], c_all[k]);
              if (s <= lim) {
                const int pos = atomicAdd(&rcnt_s[rloc], 1);
                if (pos < NSLOT)
                  gcand[(size_t)(r0 + rloc) * NSLOT + pos] =
                      make_float2(s, __int_as_float(k));
              }
            }
          }
        // reset accumulators for next chunk
#pragma unroll
        for (int a = 0; a < 2; ++a)
#pragma unroll
          for (int b = 0; b < 4; ++b) acc[a][b] = (f32x4)(0.0f);
      }
      __syncthreads();
    }
  }

  if (t < 64) {
    gmin[r0 + t] = __float_as_int(rmin_s[t]);
    gcnt[r0 + t] = rcnt_s[t];
  }
}

// ---------------------------------------------------------------------------
// k_finish v2: 4 lanes per row, exact rescore chain UNCHANGED (bit-identical
// scores -> identical indices), quad shuffle-reduce with strict-< + lowest-k.
// Also accumulates vq_loss: winner's s IS ||z-e||^2 for that row.
// ---------------------------------------------------------------------------
__global__ __launch_bounds__(256) void k_finish(
    const float* __restrict__ z, const float* __restrict__ emb,
    const float* __restrict__ cws, const float* __restrict__ aws,
    const int* __restrict__ gmin, const int* __restrict__ gcnt,
    const float2* __restrict__ gcand, int* __restrict__ idxws,
    float* __restrict__ out) {
  const int tid = (blockIdx.x << 8) + threadIdx.x;
  const int r = tid >> 2, sub = tid & 3;
  const float lim = __int_as_float(gmin[r]) + DELTA;
  int m = gcnt[r];
  if (m > NSLOT) m = NSLOT;
  const int n = r >> 10, hw = r & 1023;
  const float* zp = z + (size_t)n * 262144 + hw;
  const float a = aws[r];
  float bestv = FLT_MAX;
  int besti = 0x7fffffff;
  for (int ci = sub; ci < m; ci += 4) {
    const float2 p = gcand[(size_t)r * NSLOT + ci];
    if (p.x > lim) continue;
    const int k = __float_as_int(p.y);
    const float* ep = emb + (size_t)k * 256;
    float dot = 0.0f;
#pragma unroll 8
    for (int d = 0; d < 256; ++d) dot = fmaf(zp[(size_t)d * 1024], ep[d], dot);
    float s = fmaf(-2.0f, dot, a);  // fl(a - 2*dot)
    s = s + cws[k];                 // fl(s + c)
    if (s < bestv || (s == bestv && k < besti)) {
      bestv = s;
      besti = k;
    }
  }
#pragma unroll
  for (int off = 1; off < 4; off <<= 1) {
    const float ov = __shfl_xor(bestv, off);
    const int oi = __shfl_xor(besti, off);
    if (ov < bestv || (ov == bestv && oi < besti)) {
      bestv = ov;
      besti = oi;
    }
  }
  if (sub == 0) {
    idxws[r] = besti;
    out[OUT_IDX_OFF + r] = (float)besti;
  }
  float c = (sub == 0) ? bestv : 0.0f;
#pragma unroll
  for (int off = 1; off < 64; off <<= 1) c += __shfl_xor(c, off);
  if ((threadIdx.x & 63) == 0)
    atomicAdd(&out[OUT_LOSS_OFF], c * (1.02f / 16777216.0f));
}

// ---------------------------------------------------------------------------
// k_out2: pure z_q gather-write (unchanged). Overwrites all d_out scratch.
// ---------------------------------------------------------------------------
__global__ __launch_bounds__(256) void k_out2(const float* __restrict__ emb,
                                              const int* __restrict__ idxws,
                                              float* __restrict__ out) {
  __shared__ float zq[32][257];
  __shared__ int sidx[32];
  const int t = threadIdx.x;
  const int p0 = blockIdx.x << 5;
  const int n = p0 >> 10, hw0 = p0 & 1023;
  if (t < 32) sidx[t] = idxws[p0 + t];
  __syncthreads();
#pragma unroll
  for (int it = 0; it < 8; ++it) {
    const int i = t + (it << 8);
    const int p = i >> 6;
    const int q = (i & 63) << 2;
    const float4 v = *(const float4*)&emb[(size_t)sidx[p] * 256 + q];
    zq[p][q] = v.x;
    zq[p][q + 1] = v.y;
    zq[p][q + 2] = v.z;
    zq[p][q + 3] = v.w;
  }
  __syncthreads();
  const int p = t & 31, d0 = t >> 5;
  float* ob = out + (size_t)n * 262144 + hw0 + p;
#pragma unroll
  for (int dd = 0; dd < 32; ++dd) {
    const int d = (dd << 3) + d0;
    ob[(size_t)d * 1024] = zq[p][d];
  }
}

// ---------------------------------------------------------------------------
extern "C" void kernel_launch(void* const* d_in, const int* in_sizes, int n_in,
                              void* d_out, int out_size, void* d_ws,
                              size_t ws_size, hipStream_t stream) {
  const float* z = (const float*)d_in[0];
  const float* emb = (const float*)d_in[1];
  float* out = (float*)d_out;

  // ws layout: E2 bf16 [1024*256] | cws [1024] | aws [65536] | idx [65536]
  unsigned short* E2 = (unsigned short*)d_ws;
  float* cws = (float*)(E2 + 262144);
  float* aws = cws + 1024;
  int* idxws = (int*)(aws + 65536);
  // scratch in d_out's z_q region (k_out2 overwrites it last):
  unsigned short* A2 = (unsigned short*)d_out;
  float2* gcand = (float2*)(out + CAND_OFF);
  int* gmin = (int*)(out + GMIN_OFF);
  int* gcnt = (int*)(out + GCNT_OFF);

  // gmin/gcnt no longer need init: k_gemm3 is the single writer per row.
  hipMemsetAsync((char*)d_out + (size_t)OUT_LOSS_OFF * 4, 0, 4, stream);

  k_prep<<<dim3(1024), dim3(256), 0, stream>>>(emb, E2, cws);
  k_cvt2<<<dim3(4096), dim3(256), 0, stream>>>(z, A2);
  k_a<<<dim3(512), dim3(256), 0, stream>>>(z, aws);
  k_gemm3<<<dim3(1024), dim3(256), 0, stream>>>(A2, E2, cws, aws, gmin, gcnt,
                                                gcand);
  k_finish<<<dim3(1024), dim3(256), 0, stream>>>(z, emb, cws, aws, gmin, gcnt,
                                                 gcand, idxws, out);
  k_out2<<<dim3(2048), dim3(256), 0, stream>>>(emb, idxws, out);
}

// Round 2
// 317.931 us; speedup vs baseline: 1.1457x; 1.1457x over previous
//
#include <hip/hip_runtime.h>
#include <hip/hip_bf16.h>
#include <float.h>

// z: (64, 256, 32, 32) fp32 ; emb: (1024, 256) fp32
// M = 65536 pixels, D = 256, K = 1024 codes
// out: [z_q (16777216 f)] [indices as float (65536)] [vq_loss (1)]
#define OUT_IDX_OFF 16777216
#define OUT_LOSS_OFF 16842752
// scratch inside d_out's z_q region (overwritten by k_out at the end):
// A2 bf16: floats [0, 8388608)
// cand pairs (s,k) float2: floats [8388608, 12582912)  65536 rows x 32 slots
// gmin (int-punned f32):   floats [12582912, 13107200)
// gcnt (int):              floats [13107200, 13631488)
#define CAND_OFF 8388608
#define GMIN_OFF 12582912
#define GCNT_OFF 13107200
#define NSLOT 32
#define DELTA 2.0e-3f

typedef __attribute__((ext_vector_type(8))) short short8;
typedef __attribute__((ext_vector_type(4))) float f32x4;

static __device__ __forceinline__ unsigned short f2bf(float f) {
  union { __hip_bfloat16 h; unsigned short u; } cv;
  cv.h = __float2bfloat16(f);
  return cv.u;
}

// ---------------------------------------------------------------------------
// P1: emb -> E2 bf16 [1024 codes][256 d] + exact cws (proven r1-r4).
// ---------------------------------------------------------------------------
__global__ __launch_bounds__(256) void k_prep(const float* __restrict__ emb,
                                              unsigned short* __restrict__ E2,
                                              float* __restrict__ cws) {
  const int k = blockIdx.x, d = threadIdx.x;
  const float v = emb[k * 256 + d];
  __shared__ float red[256];
  __shared__ unsigned short row[256];
  row[d] = f2bf(v);
  red[d] = v * v;
  __syncthreads();
  for (int s = 128; s > 0; s >>= 1) {
    if (d < s) red[d] += red[d + s];
    __syncthreads();
  }
  if (d == 0) cws[k] = red[0];
  if (d < 32) ((short8*)&E2[k * 256])[d] = ((short8*)row)[d];
}

// ---------------------------------------------------------------------------
// P2 v2: z (NCHW) -> A2 bf16 [pixel][256]. (unchanged, proven)
// ---------------------------------------------------------------------------
__global__ __launch_bounds__(256) void k_cvt2(const float* __restrict__ z,
                                              unsigned short* __restrict__ A2) {
  __shared__ float tile[64][65];
  const int t = threadIdx.x;
  const int pt = blockIdx.x >> 2, dt = blockIdx.x & 3;
  const int p0 = pt << 6, d0 = dt << 6;
  const int n = p0 >> 10, hw0 = p0 & 1023;
  const float* zb = z + (size_t)n * 262144 + (size_t)d0 * 1024 + hw0;
  const int hwl = (t & 15) << 2;
#pragma unroll
  for (int i = 0; i < 4; ++i) {
    const int dl = (t >> 4) + i * 16;
    const float4 v = *(const float4*)&zb[(size_t)dl * 1024 + hwl];
    tile[hwl + 0][dl] = v.x;
    tile[hwl + 1][dl] = v.y;
    tile[hwl + 2][dl] = v.z;
    tile[hwl + 3][dl] = v.w;
  }
  __syncthreads();
  const int pl = t >> 2, c = t & 3;
  unsigned short* dst = &A2[(size_t)(p0 + pl) * 256 + d0];
#pragma unroll
  for (int h = 0; h < 2; ++h) {
    const int ch = c + h * 4;
    unsigned short tmp[8];
#pragma unroll
    for (int j = 0; j < 8; ++j) tmp[j] = f2bf(tile[pl][ch * 8 + j]);
    *(short8*)&dst[ch * 8] = *(short8*)tmp;
  }
}

// ---------------------------------------------------------------------------
// k_a: exact numpy-pairwise ||x||^2 (proven, unchanged).
// ---------------------------------------------------------------------------
__global__ __launch_bounds__(256) void k_a(const float* __restrict__ z,
                                           float* __restrict__ aws) {
#pragma clang fp contract(off)
  const int t = threadIdx.x;
  const int r = (blockIdx.x << 7) + (t & 127);
  const int h = t >> 7;
  const int n = r >> 10;
  const int hw = r & 1023;
  const float* zp = z + (size_t)n * 262144 + hw + (size_t)h * 131072;
  float acc[8];
#pragma unroll
  for (int j = 0; j < 8; ++j) {
    const float x = zp[(size_t)j * 1024];
    acc[j] = x * x;
  }
  for (int g = 1; g < 16; ++g) {
#pragma unroll
    for (int j = 0; j < 8; ++j) {
      const float x = zp[(size_t)(g * 8 + j) * 1024];
      const float p = x * x;
      acc[j] = acc[j] + p;
    }
  }
  const float s = ((acc[0] + acc[1]) + (acc[2] + acc[3])) +
                  ((acc[4] + acc[5]) + (acc[6] + acc[7]));
  __shared__ float red[256];
  red[t] = s;
  __syncthreads();
  if (t < 128) aws[(blockIdx.x << 7) + t] = red[t] + red[t + 128];
}

// ---------------------------------------------------------------------------
// k_gemm4: k_gemm2's proven 4096-block shape (128x128 tile, 16 blocks/CU of
// work -> real TLP) with the two changes validated by k_gemm3's pass:
//   1) XCD-chunked blockIdx swizzle: physical bid%8 = XCD (m09); logical
//      L = xcd*512 + bid/8 with ck fastest -> the 8 col-chunk siblings of a
//      row-block run temporally adjacent on ONE XCD, so the shared 64KB
//      A-panel stays L2-hot (miss latency 900cy -> ~200cy class).
//   2) global_load_lds staging (pre-swizzled SOURCE, linear LDS dest, m173):
//      no reg round-trip, no ds_writes, all 8 loads in flight to the barrier.
//   3) __launch_bounds__(256,4): 4 resident blocks (141KB LDS <= 160KB).
// MFMA order (kt 0..3, ks 0..1), score chain, and epilogue are BIT-IDENTICAL
// to k_gemm2 -> identical gmin/candidates; k_finish unchanged.
// ---------------------------------------------------------------------------
__global__ __launch_bounds__(256, 4) void k_gemm4(
    const unsigned short* __restrict__ A2, const unsigned short* __restrict__ E2,
    const float* __restrict__ cws, const float* __restrict__ aws,
    int* __restrict__ gmin, int* __restrict__ gcnt,
    float2* __restrict__ gcand) {
  __shared__ __align__(16) unsigned short As[128 * 64];
  __shared__ __align__(16) unsigned short Bs[128 * 64];
  __shared__ float a_l[128], c_l[128], rmkt[256], bmin[128];

  const int t = threadIdx.x;
  const int lane = t & 63;
  const int wave = __builtin_amdgcn_readfirstlane(t >> 6);
  const int wr = wave >> 1, wc = wave & 1;
  const int quad = lane >> 4, l15 = lane & 15;
  const int swa = l15 & 7;

  // XCD-chunked swizzle (grid 4096 % 8 == 0 -> simple form is bijective)
  const int bid = blockIdx.x;
  const int L = ((bid & 7) << 9) + (bid >> 3);
  const int rb = L >> 3, ck = L & 7;
  const int r0 = rb << 7, k0 = ck << 7;

  if (t < 128) {
    a_l[t] = aws[r0 + t];
    c_l[t] = cws[k0 + t];
  }

  // staging geometry: round i covers 16B-granules G = i*256 + t of the
  // [128 rows][8 granules] kt-tile; row = G>>3, physical granule gpos = G&7,
  // source granule gpos^(row&7) (involution; matches fragment-read swizzle).
  const int srow = t >> 3;  // rows advance by 32 per round
  const int gpos = t & 7;

  f32x4 acc[4][4];
#pragma unroll
  for (int a = 0; a < 4; ++a)
#pragma unroll
    for (int b = 0; b < 4; ++b) acc[a][b] = (f32x4)(0.0f);

  for (int kt = 0; kt < 4; ++kt) {
    if (kt) __syncthreads();  // waves done reading previous tiles
#pragma unroll
    for (int i = 0; i < 4; ++i) {
      const int row = (i << 5) + srow;
      const int gsrc = gpos ^ (row & 7);
      const unsigned short* sa =
          A2 + (((size_t)(r0 + row)) << 8) + (kt << 6) + (gsrc << 3);
      __builtin_amdgcn_global_load_lds(
          (const __attribute__((address_space(1))) void*)sa,
          (__attribute__((address_space(3))) void*)(As + (i << 11) +
                                                    (wave << 9)),
          16, 0, 0);
      const unsigned short* sb =
          E2 + (((size_t)(k0 + row)) << 8) + (kt << 6) + (gsrc << 3);
      __builtin_amdgcn_global_load_lds(
          (const __attribute__((address_space(1))) void*)sb,
          (__attribute__((address_space(3))) void*)(Bs + (i << 11) +
                                                    (wave << 9)),
          16, 0, 0);
    }
    __syncthreads();  // vmcnt drained -> tiles ready
#pragma unroll
    for (int ks = 0; ks < 2; ++ks) {
      short8 af[4], bf[4];
#pragma unroll
      for (int tr = 0; tr < 4; ++tr)
        af[tr] = *(const short8*)&As[(wr * 64 + tr * 16 + l15) * 64 +
                                     (((ks * 4 + quad) ^ swa) << 3)];
#pragma unroll
      for (int tc = 0; tc < 4; ++tc)
        bf[tc] = *(const short8*)&Bs[(wc * 64 + tc * 16 + l15) * 64 +
                                     (((ks * 4 + quad) ^ swa) << 3)];
#pragma unroll
      for (int tr = 0; tr < 4; ++tr)
#pragma unroll
        for (int tc = 0; tc < 4; ++tc)
          acc[tr][tc] = __builtin_amdgcn_mfma_f32_16x16x32_bf16(
              af[tr], bf[tc], acc[tr][tc], 0, 0, 0);
    }
  }

  // epilogue pass 1: chunk-local per-row min (verbatim k_gemm2)
#pragma unroll
  for (int tr = 0; tr < 4; ++tr)
#pragma unroll
    for (int rg = 0; rg < 4; ++rg) {
      const int rloc = wr * 64 + tr * 16 + quad * 4 + rg;
      const float av = a_l[rloc];
      float mn = FLT_MAX;
#pragma unroll
      for (int tc = 0; tc < 4; ++tc) {
        const int cloc = wc * 64 + tc * 16 + l15;
        const float s = av + fmaf(-2.0f, acc[tr][tc][rg], c_l[cloc]);
        mn = fminf(mn, s);
      }
      mn = fminf(mn, __shfl_xor(mn, 1));
      mn = fminf(mn, __shfl_xor(mn, 2));
      mn = fminf(mn, __shfl_xor(mn, 4));
      mn = fminf(mn, __shfl_xor(mn, 8));
      if (l15 == 0) rmkt[rloc * 2 + wc] = mn;
    }
  __syncthreads();
  if (t < 128) {
    const float m = fminf(rmkt[t * 2], rmkt[t * 2 + 1]);
    const int old = atomicMin(&gmin[r0 + t], __float_as_int(m));
    bmin[t] = fminf(m, __int_as_float(old));  // bits monotone for s>0
  }
  __syncthreads();
  // epilogue pass 2: append candidates within DELTA of tightened min
#pragma unroll
  for (int tr = 0; tr < 4; ++tr)
#pragma unroll
    for (int rg = 0; rg < 4; ++rg) {
      const int rloc = wr * 64 + tr * 16 + quad * 4 + rg;
      const float av = a_l[rloc];
      const float lim = bmin[rloc] + DELTA;
#pragma unroll
      for (int tc = 0; tc < 4; ++tc) {
        const int cloc = wc * 64 + tc * 16 + l15;
        const float s = av + fmaf(-2.0f, acc[tr][tc][rg], c_l[cloc]);
        if (s <= lim) {
          const int pos = atomicAdd(&gcnt[r0 + rloc], 1);
          if (pos < NSLOT)
            gcand[(size_t)(r0 + rloc) * NSLOT + pos] =
                make_float2(s, __int_as_float(k0 + cloc));
        }
      }
    }
}

// ---------------------------------------------------------------------------
// k_finish v2: 4 lanes per row, exact rescore chain UNCHANGED (bit-identical
// scores -> identical indices), quad shuffle-reduce with strict-< + lowest-k.
// Also accumulates vq_loss: winner's s IS ||z-e||^2 for that row.
// ---------------------------------------------------------------------------
__global__ __launch_bounds__(256) void k_finish(
    const float* __restrict__ z, const float* __restrict__ emb,
    const float* __restrict__ cws, const float* __restrict__ aws,
    const int* __restrict__ gmin, const int* __restrict__ gcnt,
    const float2* __restrict__ gcand, int* __restrict__ idxws,
    float* __restrict__ out) {
  const int tid = (blockIdx.x << 8) + threadIdx.x;
  const int r = tid >> 2, sub = tid & 3;
  const float lim = __int_as_float(gmin[r]) + DELTA;
  int m = gcnt[r];
  if (m > NSLOT) m = NSLOT;
  const int n = r >> 10, hw = r & 1023;
  const float* zp = z + (size_t)n * 262144 + hw;
  const float a = aws[r];
  float bestv = FLT_MAX;
  int besti = 0x7fffffff;
  for (int ci = sub; ci < m; ci += 4) {
    const float2 p = gcand[(size_t)r * NSLOT + ci];
    if (p.x > lim) continue;
    const int k = __float_as_int(p.y);
    const float* ep = emb + (size_t)k * 256;
    float dot = 0.0f;
#pragma unroll 8
    for (int d = 0; d < 256; ++d) dot = fmaf(zp[(size_t)d * 1024], ep[d], dot);
    float s = fmaf(-2.0f, dot, a);  // fl(a - 2*dot)
    s = s + cws[k];                 // fl(s + c)
    if (s < bestv || (s == bestv && k < besti)) {
      bestv = s;
      besti = k;
    }
  }
#pragma unroll
  for (int off = 1; off < 4; off <<= 1) {
    const float ov = __shfl_xor(bestv, off);
    const int oi = __shfl_xor(besti, off);
    if (ov < bestv || (ov == bestv && oi < besti)) {
      bestv = ov;
      besti = oi;
    }
  }
  if (sub == 0) {
    idxws[r] = besti;
    out[OUT_IDX_OFF + r] = (float)besti;
  }
  float c = (sub == 0) ? bestv : 0.0f;
#pragma unroll
  for (int off = 1; off < 64; off <<= 1) c += __shfl_xor(c, off);
  if ((threadIdx.x & 63) == 0)
    atomicAdd(&out[OUT_LOSS_OFF], c * (1.02f / 16777216.0f));
}

// ---------------------------------------------------------------------------
// k_out2: pure z_q gather-write (unchanged). Overwrites all d_out scratch.
// ---------------------------------------------------------------------------
__global__ __launch_bounds__(256) void k_out2(const float* __restrict__ emb,
                                              const int* __restrict__ idxws,
                                              float* __restrict__ out) {
  __shared__ float zq[32][257];
  __shared__ int sidx[32];
  const int t = threadIdx.x;
  const int p0 = blockIdx.x << 5;
  const int n = p0 >> 10, hw0 = p0 & 1023;
  if (t < 32) sidx[t] = idxws[p0 + t];
  __syncthreads();
#pragma unroll
  for (int it = 0; it < 8; ++it) {
    const int i = t + (it << 8);
    const int p = i >> 6;
    const int q = (i & 63) << 2;
    const float4 v = *(const float4*)&emb[(size_t)sidx[p] * 256 + q];
    zq[p][q] = v.x;
    zq[p][q + 1] = v.y;
    zq[p][q + 2] = v.z;
    zq[p][q + 3] = v.w;
  }
  __syncthreads();
  const int p = t & 31, d0 = t >> 5;
  float* ob = out + (size_t)n * 262144 + hw0 + p;
#pragma unroll
  for (int dd = 0; dd < 32; ++dd) {
    const int d = (dd << 3) + d0;
    ob[(size_t)d * 1024] = zq[p][d];
  }
}

// ---------------------------------------------------------------------------
extern "C" void kernel_launch(void* const* d_in, const int* in_sizes, int n_in,
                              void* d_out, int out_size, void* d_ws,
                              size_t ws_size, hipStream_t stream) {
  const float* z = (const float*)d_in[0];
  const float* emb = (const float*)d_in[1];
  float* out = (float*)d_out;

  // ws layout: E2 bf16 [1024*256] | cws [1024] | aws [65536] | idx [65536]
  unsigned short* E2 = (unsigned short*)d_ws;
  float* cws = (float*)(E2 + 262144);
  float* aws = cws + 1024;
  int* idxws = (int*)(aws + 65536);
  // scratch in d_out's z_q region (k_out2 overwrites it last):
  unsigned short* A2 = (unsigned short*)d_out;
  float2* gcand = (float2*)(out + CAND_OFF);
  int* gmin = (int*)(out + GMIN_OFF);
  int* gcnt = (int*)(out + GCNT_OFF);

  hipMemsetAsync((char*)d_out + (size_t)OUT_LOSS_OFF * 4, 0, 4, stream);
  hipMemsetAsync(gmin, 0x7f, 65536 * 4, stream);  // 0x7f7f7f7f ~ +inf
  hipMemsetAsync(gcnt, 0, 65536 * 4, stream);

  k_prep<<<dim3(1024), dim3(256), 0, stream>>>(emb, E2, cws);
  k_cvt2<<<dim3(4096), dim3(256), 0, stream>>>(z, A2);
  k_a<<<dim3(512), dim3(256), 0, stream>>>(z, aws);
  k_gemm4<<<dim3(4096), dim3(256), 0, stream>>>(A2, E2, cws, aws, gmin, gcnt,
                                                gcand);
  k_finish<<<dim3(1024), dim3(256), 0, stream>>>(z, emb, cws, aws, gmin, gcnt,
                                                 gcand, idxws, out);
  k_out2<<<dim3(2048), dim3(256), 0, stream>>>(emb, idxws, out);
}